// Round 8
// baseline (307.772 us; speedup 1.0000x reference)
//
#include <hip/hip_runtime.h>
#include <hip/hip_bf16.h>
#include <math.h>

#define DI __device__ __forceinline__

static constexpr float SCALE = 0.17677669529663687f;  // 1/sqrt(32)

typedef short bf16x8 __attribute__((ext_vector_type(8)));
typedef float f32x4 __attribute__((ext_vector_type(4)));

// ----------------------------- device scratch ------------------------------
__device__ unsigned short g_qwh[256 * 256],  g_qwl[256 * 256];    // qw^T * SCALE, [o][c]
__device__ unsigned short g_kvwh[512 * 256], g_kvwl[512 * 256];   // kvw^T, [o2][c]
__device__ unsigned short g_pwh[256 * 256],  g_pwl[256 * 256];    // pw^T, [o][c]
__device__ unsigned short g_wth[(size_t)256 * 4096];     // conv w^T, [o][tap*256+ci]
__device__ unsigned short g_wtl[(size_t)256 * 4096];
__device__ unsigned short g_q[(size_t)64 * 4096 * 32];   // q bf16, [bh][n][32]
__device__ unsigned short g_k[(size_t)64 * 256 * 32];    // K bf16, [bh][key][32]
__device__ unsigned short g_vt[(size_t)64 * 32 * 256];   // V^T bf16, [bh][d][key]
__device__ float g_convp[(size_t)16 * 2048 * 256];       // conv split-K partials
__device__ unsigned short g_lnh[2048 * 256], g_lnl[2048 * 256];   // LN out hi/lo
__device__ unsigned short g_attnb[(size_t)32768 * 256];  // attn out bf16, [b*n][C]

DI float bfbits2f(unsigned short b) { return __uint_as_float(((unsigned)b) << 16); }

DI unsigned short f2bf(float f) {
  unsigned u = __float_as_uint(f);
  unsigned r = (u + 0x7fffu + ((u >> 16) & 1u)) >> 16;
  return (unsigned short)r;
}

DI float4 ld_bf4(const unsigned short* p) {
  ushort4 u = *(const ushort4*)p;
  return make_float4(bfbits2f(u.x), bfbits2f(u.y), bfbits2f(u.z), bfbits2f(u.w));
}

DI float ld1(const void* p, size_t i, int f32) {
  return f32 ? ((const float*)p)[i] : bfbits2f(((const unsigned short*)p)[i]);
}

DI float4 ld4(const void* p, size_t i, int f32) {
  if (f32) return *(const float4*)((const float*)p + i);
  return ld_bf4((const unsigned short*)p + i);
}

// ---------------------------------------------------------------------------
// Inline dtype detection: scan x's first 32 words. f32 data's low mantissa
// halves decode as bf16 with |v|>=2^14 (bits>=0x4680) w.p. ~0.45/word ->
// P(miss over 32) ~5e-9. bf16 N(0,1) never exceeds ~8 (0x4100). All threads
// compute the identical flag: no reduction, no extra dispatch.
// ---------------------------------------------------------------------------
DI int detect_f32(const void* xp) {
  const unsigned* p = (const unsigned*)xp;
  unsigned m0 = 0, m1 = 0;
#pragma unroll
  for (int i = 0; i < 32; ++i) {
    unsigned w = p[i];
    unsigned lo = w & 0x7fffu, hi = (w >> 16) & 0x7fffu;
    m0 = lo > m0 ? lo : m0;
    m1 = hi > m1 ? hi : m1;
  }
  unsigned mm = m0 > m1 ? m0 : m1;
  return mm >= 0x4680u ? 1 : 0;
}

// ---------------------------------------------------------------------------
// Weight prep: blocks [0,1024): qw/kvw/pw -> transposed hi/lo;
// blocks [1024,5120): sr_w OIHW -> w^T [o][tap*256+ci] hi/lo.
// ---------------------------------------------------------------------------
__global__ void k_prep(const void* __restrict__ qw, const void* __restrict__ kvw,
                       const void* __restrict__ pwp, const void* __restrict__ srw,
                       const void* __restrict__ xp) {
  const int f32 = detect_f32(xp);
  int bid = blockIdx.x;
  if (bid < 1024) {
    int e = bid * 256 + threadIdx.x;   // over 262144
    float v;
    unsigned short *dh, *dl;
    size_t di;
    if (e < 65536) {
      int o = e >> 8, c = e & 255;
      v = ld1(qw, (size_t)c * 256 + o, f32) * SCALE;
      dh = g_qwh; dl = g_qwl; di = e;
    } else if (e < 196608) {
      int e2 = e - 65536;
      int o = e2 >> 8, c = e2 & 255;
      v = ld1(kvw, (size_t)c * 512 + o, f32);
      dh = g_kvwh; dl = g_kvwl; di = e2;
    } else {
      int e2 = e - 196608;
      int o = e2 >> 8, c = e2 & 255;
      v = ld1(pwp, (size_t)c * 256 + o, f32);
      dh = g_pwh; dl = g_pwl; di = e2;
    }
    unsigned short hi = f2bf(v);
    dh[di] = hi;
    dl[di] = f2bf(v - bfbits2f(hi));
  } else {
    int e = (bid - 1024) * 256 + threadIdx.x;   // over 1048576
    int o = e >> 12, kk = e & 4095;
    int tap = kk >> 8, ci = kk & 255;
    float v = ld1(srw, (size_t)o * 4096 + ci * 16 + tap, f32);
    unsigned short hi = f2bf(v);
    g_wth[e] = hi;
    g_wtl[e] = f2bf(v - bfbits2f(hi));
  }
}

// ---------------------------------------------------------------------------
// MFMA GEMM: block tile 64(M) x 128(N), BK=32, 256 thr (4 waves x 4m x 2n).
// Register-prefetch pipeline: next iter's A/B global loads issued between the
// barriers, overlapping the current iter's MFMAs.  LDS 30 KB -> 4-5 blocks/CU.
// MODE 0: A=x,          B=qwT  -> g_q bf16, [bh][n][32]       grid (512,2)
// MODE 1: A=x gathered, B=wtT  -> g_convp[z] f32              grid (32,2,16)
// MODE 2: A=lnh/lnl,    B=kvwT -> g_k + g_vt bf16             grid (32,4)
// MODE 3: A=attnb,      B=pwT  -> out + bias (dtype-matched)  grid (512,2)
// ---------------------------------------------------------------------------
template <int MODE>
__launch_bounds__(256, 4)
__global__ void k_mgemm(const void* __restrict__ xp,
                        const void* __restrict__ biasp, void* __restrict__ outp) {
  constexpr bool XIN = (MODE == 0 || MODE == 1);   // A comes from raw x input
  constexpr bool AH  = (MODE != 3);                // A has a lo part
  constexpr int BKROW = (MODE == 1) ? 4096 : 256;

  __shared__ __align__(16) short sa_h[64 * 40];
  __shared__ __align__(16) short sa_l[64 * 40];
  __shared__ __align__(16) short sb_h[128 * 40];
  __shared__ __align__(16) short sb_l[128 * 40];

  int f32 = 0;
  if constexpr (XIN || MODE == 3) f32 = detect_f32(xp);

  const int tid = threadIdx.x;
  const int m0 = blockIdx.x * 64;
  const int n0 = blockIdx.y * 128;
  const int kz = (MODE == 1) ? blockIdx.z * 256 : 0;
  const int wave = tid >> 6, lane = tid & 63;
  const int quad = lane >> 4, l15 = lane & 15;

  const unsigned short* Bh = (MODE == 0) ? g_qwh : (MODE == 1) ? g_wth
                           : (MODE == 2) ? g_kvwh : g_pwh;
  const unsigned short* Bl = (MODE == 0) ? g_qwl : (MODE == 1) ? g_wtl
                           : (MODE == 2) ? g_kvwl : g_pwl;

  const int arow = tid >> 2, achk = tid & 3;
  size_t abase;
  if constexpr (MODE == 1) {
    int m = m0 + arow;
    int bb = m >> 8, sp = m & 255;
    int oh = sp >> 4, ow = sp & 15;
    int tap = kz >> 8, kh = tap >> 2, kw = tap & 3;
    int n = (4 * oh + kh) * 64 + 4 * ow + kw;
    abase = (((size_t)(bb * 4096 + n)) << 8) + achk * 8;   // + it*32 (within tap)
  } else {
    abase = (((size_t)(m0 + arow)) << 8) + achk * 8;
  }

  float4 pa0, pa1;      // XIN prefetch (raw f32-or-bf16 decode)
  uint4 pah, pal;       // non-XIN prefetch
  uint4 pbh[2], pbl[2];

  auto loadAB = [&](int it) {
    size_t sa = abase + it * 32;
    if constexpr (XIN) {
      pa0 = ld4(xp, sa, f32);
      pa1 = ld4(xp, sa + 4, f32);
    } else if constexpr (MODE == 2) {
      pah = *(const uint4*)&g_lnh[sa];
      pal = *(const uint4*)&g_lnl[sa];
    } else {
      pah = *(const uint4*)&g_attnb[sa];
    }
#pragma unroll
    for (int i = 0; i < 2; ++i) {
      int lin = tid + 256 * i;
      int row = lin >> 2, chk = lin & 3;
      size_t sb = (size_t)(n0 + row) * BKROW + kz + it * 32 + chk * 8;
      pbh[i] = *(const uint4*)&Bh[sb];
      pbl[i] = *(const uint4*)&Bl[sb];
    }
  };

  auto storeLDS = [&]() {
    int ao = arow * 40 + achk * 8;
    if constexpr (XIN) {
      ushort4 h0, l0, h1, l1;
      h0.x = f2bf(pa0.x); l0.x = f2bf(pa0.x - bfbits2f(h0.x));
      h0.y = f2bf(pa0.y); l0.y = f2bf(pa0.y - bfbits2f(h0.y));
      h0.z = f2bf(pa0.z); l0.z = f2bf(pa0.z - bfbits2f(h0.z));
      h0.w = f2bf(pa0.w); l0.w = f2bf(pa0.w - bfbits2f(h0.w));
      h1.x = f2bf(pa1.x); l1.x = f2bf(pa1.x - bfbits2f(h1.x));
      h1.y = f2bf(pa1.y); l1.y = f2bf(pa1.y - bfbits2f(h1.y));
      h1.z = f2bf(pa1.z); l1.z = f2bf(pa1.z - bfbits2f(h1.z));
      h1.w = f2bf(pa1.w); l1.w = f2bf(pa1.w - bfbits2f(h1.w));
      *(ushort4*)&sa_h[ao]     = h0;
      *(ushort4*)&sa_h[ao + 4] = h1;
      *(ushort4*)&sa_l[ao]     = l0;
      *(ushort4*)&sa_l[ao + 4] = l1;
    } else if constexpr (MODE == 2) {
      *(uint4*)&sa_h[ao] = pah;
      *(uint4*)&sa_l[ao] = pal;
    } else {
      *(uint4*)&sa_h[ao] = pah;
    }
#pragma unroll
    for (int i = 0; i < 2; ++i) {
      int lin = tid + 256 * i;
      int row = lin >> 2, chk = lin & 3;
      *(uint4*)&sb_h[row * 40 + chk * 8] = pbh[i];
      *(uint4*)&sb_l[row * 40 + chk * 8] = pbl[i];
    }
  };

  f32x4 acc[4][2] = {};
  loadAB(0);
  for (int it = 0; it < 8; ++it) {
    storeLDS();
    __syncthreads();
    if (it < 7) loadAB(it + 1);   // in flight during MFMAs
#pragma unroll
    for (int mt = 0; mt < 4; ++mt) {
      bf16x8 a_h = *(const bf16x8*)&sa_h[(mt * 16 + l15) * 40 + quad * 8];
      bf16x8 a_l;
      if constexpr (AH) a_l = *(const bf16x8*)&sa_l[(mt * 16 + l15) * 40 + quad * 8];
#pragma unroll
      for (int j = 0; j < 2; ++j) {
        int nr = (wave * 2 + j) * 16 + l15;
        bf16x8 b_h = *(const bf16x8*)&sb_h[nr * 40 + quad * 8];
        bf16x8 b_l = *(const bf16x8*)&sb_l[nr * 40 + quad * 8];
        f32x4 c = acc[mt][j];
        c = __builtin_amdgcn_mfma_f32_16x16x32_bf16(a_h, b_h, c, 0, 0, 0);
        if constexpr (AH)
          c = __builtin_amdgcn_mfma_f32_16x16x32_bf16(a_l, b_h, c, 0, 0, 0);
        c = __builtin_amdgcn_mfma_f32_16x16x32_bf16(a_h, b_l, c, 0, 0, 0);
        acc[mt][j] = c;
      }
    }
    __syncthreads();
  }

  // ---- epilogue (C-layout: m = mt*16 + quad*4 + r, n = n-tile + l15) ----
#pragma unroll
  for (int mt = 0; mt < 4; ++mt) {
#pragma unroll
    for (int j = 0; j < 2; ++j) {
#pragma unroll
      for (int r = 0; r < 4; ++r) {
        int m = m0 + mt * 16 + quad * 4 + r;
        int c = n0 + (wave * 2 + j) * 16 + l15;
        float v = acc[mt][j][r];
        if constexpr (MODE == 0) {
          int b = m >> 12, n = m & 4095;
          int h = c >> 5, d = c & 31;
          g_q[(((size_t)(b * 8 + h) * 4096 + n) << 5) + d] = f2bf(v);
        } else if constexpr (MODE == 1) {
          g_convp[((size_t)blockIdx.z * 2048 + m) * 256 + c] = v;
        } else if constexpr (MODE == 2) {
          int s = c >> 8, h = (c >> 5) & 7, d = c & 31;
          int bb = m >> 8, nk = m & 255;
          if (s == 0)
            g_k[(((size_t)(bb * 8 + h) * 256 + nk) << 5) + d] = f2bf(v);
          else
            g_vt[(((size_t)(bb * 8 + h) * 32 + d) << 8) + nk] = f2bf(v);
        } else {
          float rr = v + ld1(biasp, c, f32);
          if (f32) ((float*)outp)[(size_t)m * 256 + c] = rr;
          else     ((unsigned short*)outp)[(size_t)m * 256 + c] = f2bf(rr);
        }
      }
    }
  }
}

// ---------------------------------------------------------------------------
// Fused split-K reduce + bias + LayerNorm -> lnh/lnl.  grid 2048, block 256.
// ---------------------------------------------------------------------------
__global__ void k_redln(const void* __restrict__ xp, const void* __restrict__ srb,
                        const void* __restrict__ lw, const void* __restrict__ lb) {
  const int f32 = detect_f32(xp);
  int row = blockIdx.x, t = threadIdx.x;
  size_t idx = (size_t)row * 256 + t;
  float v = 0.f;
#pragma unroll
  for (int z = 0; z < 16; ++z) v += g_convp[(size_t)z * (2048 * 256) + idx];
  v += ld1(srb, t, f32);
  float s = v, sq = v * v;
#pragma unroll
  for (int off = 32; off >= 1; off >>= 1) {
    s += __shfl_down(s, off, 64);
    sq += __shfl_down(sq, off, 64);
  }
  __shared__ float rs[4], rq[4];
  int wid = t >> 6;
  if ((t & 63) == 0) { rs[wid] = s; rq[wid] = sq; }
  __syncthreads();
  float st = rs[0] + rs[1] + rs[2] + rs[3];
  float qt = rq[0] + rq[1] + rq[2] + rq[3];
  float mu = st * (1.0f / 256.0f);
  float var = qt * (1.0f / 256.0f) - mu * mu;
  float r = rsqrtf(var + 1e-5f);
  float o = (v - mu) * r * ld1(lw, t, f32) + ld1(lb, t, f32);
  unsigned short hi = f2bf(o);
  g_lnh[idx] = hi;
  g_lnl[idx] = f2bf(o - bfbits2f(hi));
}

// ---------------------------------------------------------------------------
// MFMA attention, S^T formulation (verified r7): no P LDS round-trip.
// ---------------------------------------------------------------------------
__launch_bounds__(256, 3)
__global__ void k_attn() {
  __shared__ short smem[18688];
  short* sk  = smem;            // K [256][40]
  short* svt = smem + 10240;    // V^T [32][264]

  const int tid = threadIdx.x;
  const int bh = blockIdx.y;
  const int b = bh >> 3, h = bh & 7;

  {
    const uint4* gk = (const uint4*)(g_k + (size_t)bh * 8192);
    const uint4* gv = (const uint4*)(g_vt + (size_t)bh * 8192);
    for (int i = tid; i < 1024; i += 256) {
      int key = i >> 2, part = i & 3;
      *(uint4*)&sk[key * 40 + part * 8] = gk[i];
      int d = i >> 5, off = (i & 31) * 8;
      *(uint4*)&svt[d * 264 + off] = gv[i];
    }
  }
  __syncthreads();

  const int wave = tid >> 6, lane = tid & 63;
  const int quad = lane >> 4, l15 = lane & 15;
  const int n0 = blockIdx.x * 64 + wave * 16;

  bf16x8 qv = *(const bf16x8*)(g_q + ((size_t)bh * 4096 + n0 + l15) * 32 + quad * 8);

  f32x4 sacc[16];
#pragma unroll
  for (int t = 0; t < 16; ++t) {
    bf16x8 kf = *(const bf16x8*)&sk[(t * 16 + l15) * 40 + quad * 8];
    f32x4 c = {0.f, 0.f, 0.f, 0.f};
    sacc[t] = __builtin_amdgcn_mfma_f32_16x16x32_bf16(kf, qv, c, 0, 0, 0);
  }

  float m = sacc[0][0];
#pragma unroll
  for (int t = 0; t < 16; ++t) {
#pragma unroll
    for (int r = 0; r < 4; ++r) m = fmaxf(m, sacc[t][r]);
  }
  m = fmaxf(m, __shfl_xor(m, 16, 64));
  m = fmaxf(m, __shfl_xor(m, 32, 64));

  unsigned plo[16], phi[16];
  float ls = 0.f;
#pragma unroll
  for (int t = 0; t < 16; ++t) {
    unsigned short p0 = f2bf(__expf(sacc[t][0] - m));
    unsigned short p1 = f2bf(__expf(sacc[t][1] - m));
    unsigned short p2 = f2bf(__expf(sacc[t][2] - m));
    unsigned short p3 = f2bf(__expf(sacc[t][3] - m));
    ls += bfbits2f(p0) + bfbits2f(p1) + bfbits2f(p2) + bfbits2f(p3);
    plo[t] = (unsigned)p0 | ((unsigned)p1 << 16);
    phi[t] = (unsigned)p2 | ((unsigned)p3 << 16);
  }
  ls += __shfl_xor(ls, 16, 64);
  ls += __shfl_xor(ls, 32, 64);
  float inv = 1.0f / ls;

  f32x4 o0 = {0.f, 0.f, 0.f, 0.f}, o1 = {0.f, 0.f, 0.f, 0.f};
  const int laneA = ((quad & 1) << 5) + l15;
  const int laneB = laneA + 16;
  const bool hiT = quad >= 2;
#pragma unroll
  for (int c = 0; c < 8; ++c) {
    unsigned a0 = __shfl(plo[2 * c], laneA, 64), b0 = __shfl(plo[2 * c + 1], laneA, 64);
    unsigned a1 = __shfl(phi[2 * c], laneA, 64), b1 = __shfl(phi[2 * c + 1], laneA, 64);
    unsigned a2 = __shfl(plo[2 * c], laneB, 64), b2 = __shfl(plo[2 * c + 1], laneB, 64);
    unsigned a3 = __shfl(phi[2 * c], laneB, 64), b3 = __shfl(phi[2 * c + 1], laneB, 64);
    uint4 pk = make_uint4(hiT ? b0 : a0, hiT ? b1 : a1, hiT ? b2 : a2, hiT ? b3 : a3);
    bf16x8 pf = *(bf16x8*)&pk;
    bf16x8 v0 = *(const bf16x8*)&svt[l15 * 264 + c * 32 + quad * 8];
    bf16x8 v1 = *(const bf16x8*)&svt[(16 + l15) * 264 + c * 32 + quad * 8];
    o0 = __builtin_amdgcn_mfma_f32_16x16x32_bf16(v0, pf, o0, 0, 0, 0);
    o1 = __builtin_amdgcn_mfma_f32_16x16x32_bf16(v1, pf, o1, 0, 0, 0);
  }

  size_t base = ((size_t)(b * 4096 + n0 + l15)) * 256 + h * 32 + quad * 4;
  ushort4 u0, u1;
  u0.x = f2bf(o0[0] * inv); u0.y = f2bf(o0[1] * inv);
  u0.z = f2bf(o0[2] * inv); u0.w = f2bf(o0[3] * inv);
  u1.x = f2bf(o1[0] * inv); u1.y = f2bf(o1[1] * inv);
  u1.z = f2bf(o1[2] * inv); u1.w = f2bf(o1[3] * inv);
  *(ushort4*)&g_attnb[base]      = u0;
  *(ushort4*)&g_attnb[base + 16] = u1;
}

// ---------------------------------------------------------------------------
extern "C" void kernel_launch(void* const* d_in, const int* in_sizes, int n_in,
                              void* d_out, int out_size, void* d_ws, size_t ws_size,
                              hipStream_t stream) {
  const void* x   = d_in[0];
  const void* qw  = d_in[3];
  const void* kvw = d_in[4];
  const void* srw = d_in[5];
  const void* srb = d_in[6];
  const void* lnw = d_in[7];
  const void* lnb = d_in[8];
  const void* pw  = d_in[9];
  const void* pb  = d_in[10];

  k_prep<<<5120, 256, 0, stream>>>(qw, kvw, pw, srw, x);
  // q projection (MFMA) -> g_q
  k_mgemm<0><<<dim3(512, 2), 256, 0, stream>>>(x, nullptr, nullptr);
  // conv (MFMA, split-K z=16, one tap per z)
  k_mgemm<1><<<dim3(32, 2, 16), 256, 0, stream>>>(x, nullptr, nullptr);
  // fused reduce + bias + LN
  k_redln<<<2048, 256, 0, stream>>>(x, srb, lnw, lnb);
  // kv projection (MFMA) -> g_k / g_vt
  k_mgemm<2><<<dim3(32, 4), 256, 0, stream>>>(x, nullptr, nullptr);
  // attention (MFMA, S^T formulation)
  k_attn<<<dim3(64, 64), 256, 0, stream>>>();
  // output projection (MFMA) + bias
  k_mgemm<3><<<dim3(512, 2), 256, 0, stream>>>(x, pb, d_out);
}

// Round 10
// 235.313 us; speedup vs baseline: 1.3079x; 1.3079x over previous
//
#include <hip/hip_runtime.h>
#include <hip/hip_bf16.h>
#include <math.h>

#define DI __device__ __forceinline__

static constexpr float SCALE = 0.17677669529663687f;  // 1/sqrt(32)

typedef short bf16x8 __attribute__((ext_vector_type(8)));
typedef float f32x4 __attribute__((ext_vector_type(4)));

// ----------------------------- device scratch ------------------------------
__device__ unsigned short g_qwh[256 * 256],  g_qwl[256 * 256];    // qw^T * SCALE, [o][c]
__device__ unsigned short g_kvwh[512 * 256], g_kvwl[512 * 256];   // kvw^T, [o2][c]
__device__ unsigned short g_pwh[256 * 256],  g_pwl[256 * 256];    // pw^T, [o][c]
__device__ unsigned short g_wth[(size_t)256 * 4096];     // conv w^T, [o][tap*256+ci]
__device__ unsigned short g_wtl[(size_t)256 * 4096];
__device__ unsigned short g_q[(size_t)64 * 4096 * 32];   // q bf16, [bh][n][32]
__device__ unsigned short g_k[(size_t)64 * 256 * 32];    // K bf16, [bh][key][32]
__device__ unsigned short g_vt[(size_t)64 * 32 * 256];   // V^T bf16, [bh][d][key]
__device__ unsigned short g_convp[(size_t)16 * 2048 * 256];  // conv split-K partials (bf16)
__device__ unsigned short g_lnh[2048 * 256], g_lnl[2048 * 256];   // LN out hi/lo
__device__ unsigned short g_attnb[(size_t)32768 * 256];  // attn out bf16, [b*n][C]

DI float bfbits2f(unsigned short b) { return __uint_as_float(((unsigned)b) << 16); }

DI unsigned short f2bf(float f) {
  unsigned u = __float_as_uint(f);
  unsigned r = (u + 0x7fffu + ((u >> 16) & 1u)) >> 16;
  return (unsigned short)r;
}

DI float4 ld_bf4(const unsigned short* p) {
  ushort4 u = *(const ushort4*)p;
  return make_float4(bfbits2f(u.x), bfbits2f(u.y), bfbits2f(u.z), bfbits2f(u.w));
}

DI float ld1(const void* p, size_t i, int f32) {
  return f32 ? ((const float*)p)[i] : bfbits2f(((const unsigned short*)p)[i]);
}

DI float4 ld4(const void* p, size_t i, int f32) {
  if (f32) return *(const float4*)((const float*)p + i);
  return ld_bf4((const unsigned short*)p + i);
}

// ---------------------------------------------------------------------------
// Inline dtype detection: scan x's first 32 words (128 B, wave-uniform ->
// L1-broadcast). f32 low-mantissa halves decode as bf16 |v|>=2^14 w.p.
// ~0.45/word -> P(miss over 32) ~5e-9. bf16 N(0,1) never exceeds ~8.
// NOTE: must be called with the RAW INPUT pointer (d_in[0]); passing a
// __device__ symbol from host code crashes (r9 post-mortem).
// ---------------------------------------------------------------------------
DI int detect_f32(const void* xp) {
  const unsigned* p = (const unsigned*)xp;
  unsigned m0 = 0, m1 = 0;
#pragma unroll
  for (int i = 0; i < 32; ++i) {
    unsigned w = p[i];
    unsigned lo = w & 0x7fffu, hi = (w >> 16) & 0x7fffu;
    m0 = lo > m0 ? lo : m0;
    m1 = hi > m1 ? hi : m1;
  }
  unsigned mm = m0 > m1 ? m0 : m1;
  return mm >= 0x4680u ? 1 : 0;
}

// ---------------------------------------------------------------------------
// Weight prep: blocks [0,1024): qw/kvw/pw -> transposed hi/lo;
// blocks [1024,5120): sr_w OIHW -> w^T [o][tap*256+ci] hi/lo.
// ---------------------------------------------------------------------------
__global__ void k_prep(const void* __restrict__ qw, const void* __restrict__ kvw,
                       const void* __restrict__ pwp, const void* __restrict__ srw,
                       const void* __restrict__ xp) {
  const int f32 = detect_f32(xp);
  int bid = blockIdx.x;
  if (bid < 1024) {
    int e = bid * 256 + threadIdx.x;   // over 262144
    float v;
    unsigned short *dh, *dl;
    size_t di;
    if (e < 65536) {
      int o = e >> 8, c = e & 255;
      v = ld1(qw, (size_t)c * 256 + o, f32) * SCALE;
      dh = g_qwh; dl = g_qwl; di = e;
    } else if (e < 196608) {
      int e2 = e - 65536;
      int o = e2 >> 8, c = e2 & 255;
      v = ld1(kvw, (size_t)c * 512 + o, f32);
      dh = g_kvwh; dl = g_kvwl; di = e2;
    } else {
      int e2 = e - 196608;
      int o = e2 >> 8, c = e2 & 255;
      v = ld1(pwp, (size_t)c * 256 + o, f32);
      dh = g_pwh; dl = g_pwl; di = e2;
    }
    unsigned short hi = f2bf(v);
    dh[di] = hi;
    dl[di] = f2bf(v - bfbits2f(hi));
  } else {
    int e = (bid - 1024) * 256 + threadIdx.x;   // over 1048576
    int o = e >> 12, kk = e & 4095;
    int tap = kk >> 8, ci = kk & 255;
    float v = ld1(srw, (size_t)o * 4096 + ci * 16 + tap, f32);
    unsigned short hi = f2bf(v);
    g_wth[e] = hi;
    g_wtl[e] = f2bf(v - bfbits2f(hi));
  }
}

// ---------------------------------------------------------------------------
// MFMA GEMM (r7-measured design): block tile 64(M) x 256(N), BK=32, 256 thr
// (4 waves x 4m x 4n).  LDS 51.2 KB -> 3 blocks/CU.  No prefetch (the r8
// 64x128+prefetch variant regressed 241->308 us).
// MODE 0: A=x,          B=qwT  -> g_q bf16, [bh][n][32]       grid (512,1)
// MODE 1: A=x gathered, B=wtT  -> g_convp[z] bf16             grid (32,1,16)
// MODE 2: A=lnh/lnl,    B=kvwT -> g_k + g_vt bf16 (nblk 0/1)  grid (32,2)
// MODE 3: A=attnb,      B=pwT  -> out + bias; Ax = x (detect only)
// ---------------------------------------------------------------------------
template <int MODE>
__launch_bounds__(256, 3)
__global__ void k_mgemm(const void* __restrict__ Ax,
                        const void* __restrict__ biasp, void* __restrict__ outp) {
  constexpr bool XIN = (MODE == 0 || MODE == 1);   // A comes from raw x input
  constexpr bool AH  = (MODE != 3);                // A has a lo part
  constexpr int BKROW = (MODE == 1) ? 4096 : 256;

  __shared__ __align__(16) short sa_h[64 * 40];
  __shared__ __align__(16) short sa_l[64 * 40];
  __shared__ __align__(16) short sb_h[256 * 40];
  __shared__ __align__(16) short sb_l[256 * 40];

  int f32 = 0;
  if constexpr (XIN || MODE == 3) f32 = detect_f32(Ax);

  const int tid = threadIdx.x;
  const int m0 = blockIdx.x * 64;
  const int nblk = (MODE == 2) ? blockIdx.y : 0;
  const int kz = (MODE == 1) ? blockIdx.z * 256 : 0;
  const int wave = tid >> 6, lane = tid & 63;
  const int quad = lane >> 4, l15 = lane & 15;

  const unsigned short* Bh = (MODE == 0) ? g_qwh : (MODE == 1) ? g_wth
                           : (MODE == 2) ? g_kvwh : g_pwh;
  const unsigned short* Bl = (MODE == 0) ? g_qwl : (MODE == 1) ? g_wtl
                           : (MODE == 2) ? g_kvwl : g_pwl;

  f32x4 acc[4][4] = {};

  for (int it = 0; it < 8; ++it) {
    const int kb = kz + it * 32;
    // ---- stage A: 64 rows x 32 k ----
    {
      int row = tid >> 2, chunk = tid & 3;
      size_t src;
      if constexpr (MODE == 1) {
        int m = m0 + row;
        int bb = m >> 8, sp = m & 255;
        int oh = sp >> 4, ow = sp & 15;
        int tap = kb >> 8, kh = tap >> 2, kw = tap & 3;
        int n = (4 * oh + kh) * 64 + 4 * ow + kw;
        src = (((size_t)(bb * 4096 + n)) << 8) + (kb & 255) + chunk * 8;
      } else {
        src = (((size_t)(m0 + row)) << 8) + kb + chunk * 8;
      }
      if constexpr (XIN) {
        float4 v0 = ld4(Ax, src, f32);
        float4 v1 = ld4(Ax, src + 4, f32);
        ushort4 h0, l0, h1, l1;
        h0.x = f2bf(v0.x); l0.x = f2bf(v0.x - bfbits2f(h0.x));
        h0.y = f2bf(v0.y); l0.y = f2bf(v0.y - bfbits2f(h0.y));
        h0.z = f2bf(v0.z); l0.z = f2bf(v0.z - bfbits2f(h0.z));
        h0.w = f2bf(v0.w); l0.w = f2bf(v0.w - bfbits2f(h0.w));
        h1.x = f2bf(v1.x); l1.x = f2bf(v1.x - bfbits2f(h1.x));
        h1.y = f2bf(v1.y); l1.y = f2bf(v1.y - bfbits2f(h1.y));
        h1.z = f2bf(v1.z); l1.z = f2bf(v1.z - bfbits2f(h1.z));
        h1.w = f2bf(v1.w); l1.w = f2bf(v1.w - bfbits2f(h1.w));
        *(ushort4*)&sa_h[row * 40 + chunk * 8]     = h0;
        *(ushort4*)&sa_h[row * 40 + chunk * 8 + 4] = h1;
        *(ushort4*)&sa_l[row * 40 + chunk * 8]     = l0;
        *(ushort4*)&sa_l[row * 40 + chunk * 8 + 4] = l1;
      } else if constexpr (MODE == 2) {
        *(uint4*)&sa_h[row * 40 + chunk * 8] = *(const uint4*)&g_lnh[src];
        *(uint4*)&sa_l[row * 40 + chunk * 8] = *(const uint4*)&g_lnl[src];
      } else {
        *(uint4*)&sa_h[row * 40 + chunk * 8] = *(const uint4*)&g_attnb[src];
      }
    }
    // ---- stage B: 256 rows x 32 k ----
    {
#pragma unroll
      for (int i = 0; i < 4; ++i) {
        int lin = tid + 256 * i;
        int row = lin >> 2, chk = lin & 3;
        size_t src = (size_t)(nblk * 256 + row) * BKROW + kb + chk * 8;
        *(uint4*)&sb_h[row * 40 + chk * 8] = *(const uint4*)&Bh[src];
        *(uint4*)&sb_l[row * 40 + chk * 8] = *(const uint4*)&Bl[src];
      }
    }
    __syncthreads();
    // ---- mfma ----
#pragma unroll
    for (int mt = 0; mt < 4; ++mt) {
      bf16x8 a_h = *(const bf16x8*)&sa_h[(mt * 16 + l15) * 40 + quad * 8];
      bf16x8 a_l;
      if constexpr (AH) a_l = *(const bf16x8*)&sa_l[(mt * 16 + l15) * 40 + quad * 8];
#pragma unroll
      for (int j = 0; j < 4; ++j) {
        int nr = (4 * wave + j) * 16 + l15;
        bf16x8 b_h = *(const bf16x8*)&sb_h[nr * 40 + quad * 8];
        bf16x8 b_l = *(const bf16x8*)&sb_l[nr * 40 + quad * 8];
        f32x4 c = acc[mt][j];
        c = __builtin_amdgcn_mfma_f32_16x16x32_bf16(a_h, b_h, c, 0, 0, 0);
        if constexpr (AH)
          c = __builtin_amdgcn_mfma_f32_16x16x32_bf16(a_l, b_h, c, 0, 0, 0);
        c = __builtin_amdgcn_mfma_f32_16x16x32_bf16(a_h, b_l, c, 0, 0, 0);
        acc[mt][j] = c;
      }
    }
    __syncthreads();
  }

  // ---- epilogue (C-layout: m = mt*16 + quad*4 + r, n = tile n + l15) ----
  const int f32o = f32;
#pragma unroll
  for (int mt = 0; mt < 4; ++mt) {
#pragma unroll
    for (int j = 0; j < 4; ++j) {
#pragma unroll
      for (int r = 0; r < 4; ++r) {
        int m = m0 + mt * 16 + quad * 4 + r;
        int c = nblk * 256 + (4 * wave + j) * 16 + l15;
        float v = acc[mt][j][r];
        if constexpr (MODE == 0) {
          int b = m >> 12, n = m & 4095;
          int h = c >> 5, d = c & 31;
          g_q[(((size_t)(b * 8 + h) * 4096 + n) << 5) + d] = f2bf(v);
        } else if constexpr (MODE == 1) {
          g_convp[((size_t)blockIdx.z * 2048 + m) * 256 + c] = f2bf(v);
        } else if constexpr (MODE == 2) {
          int s = c >> 8, h = (c >> 5) & 7, d = c & 31;
          int bb = m >> 8, nk = m & 255;
          if (s == 0)
            g_k[(((size_t)(bb * 8 + h) * 256 + nk) << 5) + d] = f2bf(v);
          else
            g_vt[(((size_t)(bb * 8 + h) * 32 + d) << 8) + nk] = f2bf(v);
        } else {
          float rr = v + ld1(biasp, c, f32o);
          if (f32o) ((float*)outp)[(size_t)m * 256 + c] = rr;
          else      ((unsigned short*)outp)[(size_t)m * 256 + c] = f2bf(rr);
        }
      }
    }
  }
}

// ---------------------------------------------------------------------------
// Fused split-K reduce (bf16 partials) + bias + LayerNorm -> lnh/lnl.
// ---------------------------------------------------------------------------
__global__ void k_redln(const void* __restrict__ xp, const void* __restrict__ srb,
                        const void* __restrict__ lw, const void* __restrict__ lb) {
  const int f32 = detect_f32(xp);
  int row = blockIdx.x, t = threadIdx.x;
  size_t idx = (size_t)row * 256 + t;
  float v = 0.f;
#pragma unroll
  for (int z = 0; z < 16; ++z) v += bfbits2f(g_convp[(size_t)z * (2048 * 256) + idx]);
  v += ld1(srb, t, f32);
  float s = v, sq = v * v;
#pragma unroll
  for (int off = 32; off >= 1; off >>= 1) {
    s += __shfl_down(s, off, 64);
    sq += __shfl_down(sq, off, 64);
  }
  __shared__ float rs[4], rq[4];
  int wid = t >> 6;
  if ((t & 63) == 0) { rs[wid] = s; rq[wid] = sq; }
  __syncthreads();
  float st = rs[0] + rs[1] + rs[2] + rs[3];
  float qt = rq[0] + rq[1] + rq[2] + rq[3];
  float mu = st * (1.0f / 256.0f);
  float var = qt * (1.0f / 256.0f) - mu * mu;
  float r = rsqrtf(var + 1e-5f);
  float o = (v - mu) * r * ld1(lw, t, f32) + ld1(lb, t, f32);
  unsigned short hi = f2bf(o);
  g_lnh[idx] = hi;
  g_lnl[idx] = f2bf(o - bfbits2f(hi));
}

// ---------------------------------------------------------------------------
// MFMA attention, S^T formulation (verified r7): no P LDS round-trip.
// LDS 36.5 KB -> 4 blocks/CU.
// ---------------------------------------------------------------------------
__launch_bounds__(256, 4)
__global__ void k_attn() {
  __shared__ short smem[18688];
  short* sk  = smem;            // K [256][40]
  short* svt = smem + 10240;    // V^T [32][264]

  const int tid = threadIdx.x;
  const int bh = blockIdx.y;
  const int b = bh >> 3, h = bh & 7;

  {
    const uint4* gk = (const uint4*)(g_k + (size_t)bh * 8192);
    const uint4* gv = (const uint4*)(g_vt + (size_t)bh * 8192);
    for (int i = tid; i < 1024; i += 256) {
      int key = i >> 2, part = i & 3;
      *(uint4*)&sk[key * 40 + part * 8] = gk[i];
      int d = i >> 5, off = (i & 31) * 8;
      *(uint4*)&svt[d * 264 + off] = gv[i];
    }
  }
  __syncthreads();

  const int wave = tid >> 6, lane = tid & 63;
  const int quad = lane >> 4, l15 = lane & 15;
  const int n0 = blockIdx.x * 64 + wave * 16;

  bf16x8 qv = *(const bf16x8*)(g_q + ((size_t)bh * 4096 + n0 + l15) * 32 + quad * 8);

  f32x4 sacc[16];
#pragma unroll
  for (int t = 0; t < 16; ++t) {
    bf16x8 kf = *(const bf16x8*)&sk[(t * 16 + l15) * 40 + quad * 8];
    f32x4 c = {0.f, 0.f, 0.f, 0.f};
    sacc[t] = __builtin_amdgcn_mfma_f32_16x16x32_bf16(kf, qv, c, 0, 0, 0);
  }

  float m = sacc[0][0];
#pragma unroll
  for (int t = 0; t < 16; ++t) {
#pragma unroll
    for (int r = 0; r < 4; ++r) m = fmaxf(m, sacc[t][r]);
  }
  m = fmaxf(m, __shfl_xor(m, 16, 64));
  m = fmaxf(m, __shfl_xor(m, 32, 64));

  unsigned plo[16], phi[16];
  float ls = 0.f;
#pragma unroll
  for (int t = 0; t < 16; ++t) {
    unsigned short p0 = f2bf(__expf(sacc[t][0] - m));
    unsigned short p1 = f2bf(__expf(sacc[t][1] - m));
    unsigned short p2 = f2bf(__expf(sacc[t][2] - m));
    unsigned short p3 = f2bf(__expf(sacc[t][3] - m));
    ls += bfbits2f(p0) + bfbits2f(p1) + bfbits2f(p2) + bfbits2f(p3);
    plo[t] = (unsigned)p0 | ((unsigned)p1 << 16);
    phi[t] = (unsigned)p2 | ((unsigned)p3 << 16);
  }
  ls += __shfl_xor(ls, 16, 64);
  ls += __shfl_xor(ls, 32, 64);
  float inv = 1.0f / ls;

  f32x4 o0 = {0.f, 0.f, 0.f, 0.f}, o1 = {0.f, 0.f, 0.f, 0.f};
  const int laneA = ((quad & 1) << 5) + l15;
  const int laneB = laneA + 16;
  const bool hiT = quad >= 2;
#pragma unroll
  for (int c = 0; c < 8; ++c) {
    unsigned a0 = __shfl(plo[2 * c], laneA, 64), b0 = __shfl(plo[2 * c + 1], laneA, 64);
    unsigned a1 = __shfl(phi[2 * c], laneA, 64), b1 = __shfl(phi[2 * c + 1], laneA, 64);
    unsigned a2 = __shfl(plo[2 * c], laneB, 64), b2 = __shfl(plo[2 * c + 1], laneB, 64);
    unsigned a3 = __shfl(phi[2 * c], laneB, 64), b3 = __shfl(phi[2 * c + 1], laneB, 64);
    uint4 pk = make_uint4(hiT ? b0 : a0, hiT ? b1 : a1, hiT ? b2 : a2, hiT ? b3 : a3);
    bf16x8 pf = *(bf16x8*)&pk;
    bf16x8 v0 = *(const bf16x8*)&svt[l15 * 264 + c * 32 + quad * 8];
    bf16x8 v1 = *(const bf16x8*)&svt[(16 + l15) * 264 + c * 32 + quad * 8];
    o0 = __builtin_amdgcn_mfma_f32_16x16x32_bf16(v0, pf, o0, 0, 0, 0);
    o1 = __builtin_amdgcn_mfma_f32_16x16x32_bf16(v1, pf, o1, 0, 0, 0);
  }

  size_t base = ((size_t)(b * 4096 + n0 + l15)) * 256 + h * 32 + quad * 4;
  ushort4 u0, u1;
  u0.x = f2bf(o0[0] * inv); u0.y = f2bf(o0[1] * inv);
  u0.z = f2bf(o0[2] * inv); u0.w = f2bf(o0[3] * inv);
  u1.x = f2bf(o1[0] * inv); u1.y = f2bf(o1[1] * inv);
  u1.z = f2bf(o1[2] * inv); u1.w = f2bf(o1[3] * inv);
  *(ushort4*)&g_attnb[base]      = u0;
  *(ushort4*)&g_attnb[base + 16] = u1;
}

// ---------------------------------------------------------------------------
extern "C" void kernel_launch(void* const* d_in, const int* in_sizes, int n_in,
                              void* d_out, int out_size, void* d_ws, size_t ws_size,
                              hipStream_t stream) {
  const void* x   = d_in[0];
  const void* qw  = d_in[3];
  const void* kvw = d_in[4];
  const void* srw = d_in[5];
  const void* srb = d_in[6];
  const void* lnw = d_in[7];
  const void* lnb = d_in[8];
  const void* pw  = d_in[9];
  const void* pb  = d_in[10];

  k_prep<<<5120, 256, 0, stream>>>(qw, kvw, pw, srw, x);
  // q projection (MFMA) -> g_q
  k_mgemm<0><<<dim3(512, 1), 256, 0, stream>>>(x, nullptr, nullptr);
  // conv (MFMA, split-K z=16, one tap per z, bf16 partials)
  k_mgemm<1><<<dim3(32, 1, 16), 256, 0, stream>>>(x, nullptr, nullptr);
  // fused reduce + bias + LN
  k_redln<<<2048, 256, 0, stream>>>(x, srb, lnw, lnb);
  // kv projection (MFMA) -> g_k / g_vt
  k_mgemm<2><<<dim3(32, 2), 256, 0, stream>>>(nullptr, nullptr, nullptr);
  // attention (MFMA, S^T formulation)
  k_attn<<<dim3(64, 64), 256, 0, stream>>>();
  // output projection (MFMA) + bias; x passed for dtype detection only
  k_mgemm<3><<<dim3(512, 1), 256, 0, stream>>>(x, pb, d_out);
}